// Round 2
// baseline (1357.265 us; speedup 1.0000x reference)
//
#include <hip/hip_runtime.h>
#include <math.h>

#define N_NODES 100000
#define N_EDGES 3200000
#define DIM_IN 128
#define HL 32
#define DIM_OUT 40
#define BN_EPS 1e-5f

// ---------------- Wc = W @ c1_W1  (128x128 @ 128x32) ----------------
__global__ __launch_bounds__(256) void k_wc(const float* __restrict__ W,
                                            const float* __restrict__ W1,
                                            float* __restrict__ Wc) {
    int idx = blockIdx.x * 256 + threadIdx.x;   // 0..4095
    int i = idx >> 5;   // 0..127
    int j = idx & 31;   // 0..31
    float acc = 0.f;
    for (int k = 0; k < DIM_IN; ++k) acc += W[i * DIM_IN + k] * W1[k * HL + j];
    Wc[i * HL + j] = acc;
}

// ---------------- u = x @ Wc  ([N,128] @ [128,32]), 64 nodes/block ----------------
__global__ __launch_bounds__(256) void k_xproj(const float* __restrict__ x,
                                               const float* __restrict__ Wc,
                                               float* __restrict__ u) {
    __shared__ float xs[64][132];     // padded: row stride 132 -> bank shift 4
    __shared__ float Ws[DIM_IN * HL]; // 16 KB
    int t = threadIdx.x;
    int base = blockIdx.x * 64;
    for (int i = t; i < DIM_IN * HL / 4; i += 256)
        ((float4*)Ws)[i] = ((const float4*)Wc)[i];
    for (int i = t; i < 64 * 32; i += 256) {     // 2048 float4s
        int r = i >> 5, c4 = i & 31;
        float4 val;
        if (base + r < N_NODES) val = ((const float4*)x)[(size_t)(base + r) * 32 + c4];
        else val = make_float4(0.f, 0.f, 0.f, 0.f);
        *(float4*)&xs[r][c4 * 4] = val;
    }
    __syncthreads();
    int mg = t >> 3;      // 0..31 -> nodes 2mg, 2mg+1
    int cg = t & 7;       // cols cg*4..+3
    int n0 = mg * 2;
    float4 a0 = make_float4(0.f, 0.f, 0.f, 0.f);
    float4 a1 = make_float4(0.f, 0.f, 0.f, 0.f);
    for (int k = 0; k < DIM_IN; ++k) {
        float x0 = xs[n0][k], x1 = xs[n0 + 1][k];
        float4 b = ((float4*)Ws)[k * 8 + cg];
        a0.x += x0 * b.x; a0.y += x0 * b.y; a0.z += x0 * b.z; a0.w += x0 * b.w;
        a1.x += x1 * b.x; a1.y += x1 * b.y; a1.z += x1 * b.z; a1.w += x1 * b.w;
    }
    int node = base + n0;
    if (node < N_NODES)     ((float4*)u)[(size_t)node * 8 + cg] = a0;
    if (node + 1 < N_NODES) ((float4*)u)[(size_t)(node + 1) * 8 + cg] = a1;
}

// ---------------- CSR build ----------------
__global__ void k_count(const int* __restrict__ dst, int* __restrict__ deg) {
    int e = blockIdx.x * 256 + threadIdx.x;
    if (e < N_EDGES) atomicAdd(&deg[dst[e]], 1);
}

__global__ __launch_bounds__(256) void k_scan1(const int* __restrict__ deg,
                                               int* __restrict__ row_ptr,
                                               int* __restrict__ bsums) {
    __shared__ int s[256];
    int t = threadIdx.x;
    int i = blockIdx.x * 256 + t;
    int val = (i < N_NODES) ? deg[i] : 0;
    s[t] = val;
    __syncthreads();
    for (int off = 1; off < 256; off <<= 1) {
        int a = 0;
        if (t >= off) a = s[t - off];
        __syncthreads();
        s[t] += a;
        __syncthreads();
    }
    if (i < N_NODES) row_ptr[i] = s[t] - val;
    if (t == 255) bsums[blockIdx.x] = s[255];
}

__global__ __launch_bounds__(512) void k_scan2(const int* __restrict__ bsums,
                                               int* __restrict__ boffs, int nb) {
    __shared__ int s[512];
    int t = threadIdx.x;
    int val = (t < nb) ? bsums[t] : 0;
    s[t] = val;
    __syncthreads();
    for (int off = 1; off < 512; off <<= 1) {
        int a = 0;
        if (t >= off) a = s[t - off];
        __syncthreads();
        s[t] += a;
        __syncthreads();
    }
    if (t < nb) boffs[t] = s[t] - val;
}

__global__ void k_scan3(int* __restrict__ row_ptr, const int* __restrict__ boffs,
                        int* __restrict__ cursor) {
    int i = blockIdx.x * 256 + threadIdx.x;
    if (i < N_NODES) {
        int v = row_ptr[i] + boffs[i >> 8];
        row_ptr[i] = v;
        cursor[i] = v;
    }
    if (i == 0) row_ptr[N_NODES] = N_EDGES;
}

__global__ void k_scatter(const int* __restrict__ src, const int* __restrict__ dst,
                          int* __restrict__ cursor, int* __restrict__ srcs) {
    int e = blockIdx.x * 256 + threadIdx.x;
    if (e < N_EDGES) {
        int p = atomicAdd(&cursor[dst[e]], 1);
        srcs[p] = src[e];
    }
}

// ---- fused conv: gather-agg (+W1) + BN + ReLU + @W2 + b2 + ReLU -> hcat slice ----
// W1 == nullptr for conv1 (input already projected into u-space).
__global__ __launch_bounds__(256) void k_conv(const float* __restrict__ hsrc, int sstride,
                                              const int* __restrict__ row_ptr,
                                              const int* __restrict__ srcs,
                                              const float* __restrict__ W1,
                                              const float* __restrict__ b1,
                                              const float* __restrict__ g,
                                              const float* __restrict__ be,
                                              const float* __restrict__ m,
                                              const float* __restrict__ v,
                                              const float* __restrict__ W2,
                                              const float* __restrict__ b2,
                                              float* __restrict__ hout) {
    __shared__ float W1s[HL * HL];
    __shared__ float W2s[HL * HL];
    __shared__ float as_[8][HL + 1];
    __shared__ float ts[8][HL + 1];
    int t = threadIdx.x;
    bool hasW1 = (W1 != nullptr);
    for (int i = t; i < HL * HL; i += 256) {
        W2s[i] = W2[i];
        if (hasW1) W1s[i] = W1[i];
    }
    int slot = t >> 5, d = t & 31;
    int node = blockIdx.x * 8 + slot;
    float A = 0.f;
    int e0 = 0, e1 = 0;
    if (node < N_NODES) {
        A = hsrc[(size_t)node * sstride + d];
        e0 = row_ptr[node];
        e1 = row_ptr[node + 1];
    }
    for (int base = e0; base < e1; base += 32) {
        int p = base + d;
        int idx = srcs[p < e1 ? p : e1 - 1];
        int cnt = e1 - base; if (cnt > 32) cnt = 32;
        float a0 = 0.f, a1 = 0.f, a2 = 0.f, a3 = 0.f;
        int j = 0;
        for (; j + 4 <= cnt; j += 4) {
            int s0 = __shfl(idx, j + 0, 32);
            int s1 = __shfl(idx, j + 1, 32);
            int s2 = __shfl(idx, j + 2, 32);
            int s3 = __shfl(idx, j + 3, 32);
            a0 += hsrc[(size_t)s0 * sstride + d];
            a1 += hsrc[(size_t)s1 * sstride + d];
            a2 += hsrc[(size_t)s2 * sstride + d];
            a3 += hsrc[(size_t)s3 * sstride + d];
        }
        for (; j < cnt; ++j) a0 += hsrc[(size_t)__shfl(idx, j, 32) * sstride + d];
        A += (a0 + a1) + (a2 + a3);
    }
    // folded BN affine: t = (A@W1)*s + beta
    float s = g[d] * rsqrtf(v[d] + BN_EPS);
    float beta = (b1[d] - m[d]) * s + be[d];
    float tval;
    if (hasW1) {
        as_[slot][d] = A;
        __syncthreads();
        float acc = 0.f;
        #pragma unroll
        for (int k = 0; k < HL; ++k) acc += as_[slot][k] * W1s[k * HL + d];
        tval = fmaxf(acc * s + beta, 0.f);
    } else {
        tval = fmaxf(A * s + beta, 0.f);
        __syncthreads();   // match barrier count (hasW1 is block-uniform anyway)
    }
    ts[slot][d] = tval;
    __syncthreads();
    float h = b2[d];
    #pragma unroll
    for (int k = 0; k < HL; ++k) h += ts[slot][k] * W2s[k * HL + d];
    if (node < N_NODES) hout[(size_t)node * DIM_IN + d] = fmaxf(h, 0.f);
}

// ---------------- final: lin1 + ReLU + lin2 + log_softmax (tiled GEMM) ----------------
__global__ __launch_bounds__(256) void k_final(const float* __restrict__ hcat,
                                               const float* __restrict__ W1,
                                               const float* __restrict__ b1,
                                               const float* __restrict__ W2,
                                               const float* __restrict__ b2,
                                               float* __restrict__ out) {
    __shared__ float sh_h[64][132];   // 33792 B, row stride 132 (bank shift 4)
    __shared__ float shW[5120];       // 20480 B: W1 chunk (4096) / W2 full (5120)
    int t = threadIdx.x;
    int base = blockIdx.x * 64;
    // stage 64x128 hcat tile
    for (int i = t; i < 2048; i += 256) {
        int r = i >> 5, c4 = i & 31;
        float4 val;
        if (base + r < N_NODES) val = ((const float4*)hcat)[(size_t)(base + r) * 32 + c4];
        else val = make_float4(0.f, 0.f, 0.f, 0.f);
        *(float4*)&sh_h[r][c4 * 4] = val;
    }
    int cg = t & 31, ng = t >> 5;
    int c0 = cg * 4, n0 = ng * 8;
    float acc[8][4];
    float4 bias = ((const float4*)b1)[cg];
    #pragma unroll
    for (int i = 0; i < 8; ++i) {
        acc[i][0] = bias.x; acc[i][1] = bias.y; acc[i][2] = bias.z; acc[i][3] = bias.w;
    }
    // lin1: K chunked by 32
    for (int kk = 0; kk < DIM_IN; kk += 32) {
        __syncthreads();
        for (int i = t; i < 1024; i += 256)
            ((float4*)shW)[i] = ((const float4*)W1)[(size_t)(kk + (i >> 5)) * 32 + (i & 31)];
        __syncthreads();
        for (int k = 0; k < 32; ++k) {
            float4 b = ((float4*)shW)[k * 32 + cg];
            #pragma unroll
            for (int i = 0; i < 8; ++i) {
                float a = sh_h[n0 + i][kk + k];
                acc[i][0] += a * b.x; acc[i][1] += a * b.y;
                acc[i][2] += a * b.z; acc[i][3] += a * b.w;
            }
        }
    }
    __syncthreads();
    // relu(t) back into sh_h; stage W2
    #pragma unroll
    for (int i = 0; i < 8; ++i) {
        float4 vv = make_float4(fmaxf(acc[i][0], 0.f), fmaxf(acc[i][1], 0.f),
                                fmaxf(acc[i][2], 0.f), fmaxf(acc[i][3], 0.f));
        *(float4*)&sh_h[n0 + i][c0] = vv;
    }
    for (int i = t; i < 1280; i += 256) ((float4*)shW)[i] = ((const float4*)W2)[i];
    __syncthreads();
    // lin2: thread -> nodes {nn, nn+32}, cols c2..c2+4
    int cg2 = t & 7, nn = t >> 3;
    int c2 = cg2 * 5;
    float acc2[2][5];
    #pragma unroll
    for (int j = 0; j < 5; ++j) {
        float bb = b2[c2 + j];
        acc2[0][j] = bb; acc2[1][j] = bb;
    }
    for (int k = 0; k < DIM_IN; ++k) {
        float a0 = sh_h[nn][k], a1 = sh_h[nn + 32][k];
        #pragma unroll
        for (int j = 0; j < 5; ++j) {
            float w = shW[k * 40 + c2 + j];
            acc2[0][j] += a0 * w;
            acc2[1][j] += a1 * w;
        }
    }
    // log_softmax across the 8 lanes owning each node (xor-reduce width 8)
    #pragma unroll
    for (int half = 0; half < 2; ++half) {
        int node = base + nn + half * 32;
        float mx = acc2[half][0];
        #pragma unroll
        for (int j = 1; j < 5; ++j) mx = fmaxf(mx, acc2[half][j]);
        for (int off = 1; off < 8; off <<= 1) mx = fmaxf(mx, __shfl_xor(mx, off, 8));
        float sm = 0.f;
        #pragma unroll
        for (int j = 0; j < 5; ++j) sm += expf(acc2[half][j] - mx);
        for (int off = 1; off < 8; off <<= 1) sm += __shfl_xor(sm, off, 8);
        float lz = mx + logf(sm);
        if (node < N_NODES) {
            #pragma unroll
            for (int j = 0; j < 5; ++j) {
                float o = acc2[half][j];
                out[(size_t)node * DIM_OUT + c2 + j] = o;
                out[(size_t)N_NODES * DIM_OUT + (size_t)node * DIM_OUT + c2 + j] = o - lz;
            }
        }
    }
}

extern "C" void kernel_launch(void* const* d_in, const int* in_sizes, int n_in,
                              void* d_out, int out_size, void* d_ws, size_t ws_size,
                              hipStream_t stream) {
    const float* x      = (const float*)d_in[0];
    const int*   ei     = (const int*)d_in[1];
    const float* W      = (const float*)d_in[2];
    const float* c1_W1  = (const float*)d_in[3];
    const float* c1_b1  = (const float*)d_in[4];
    const float* c1_g   = (const float*)d_in[5];
    const float* c1_be  = (const float*)d_in[6];
    const float* c1_m   = (const float*)d_in[7];
    const float* c1_v   = (const float*)d_in[8];
    const float* c1_W2  = (const float*)d_in[9];
    const float* c1_b2  = (const float*)d_in[10];
    const float* cW1    = (const float*)d_in[11];
    const float* cb1    = (const float*)d_in[12];
    const float* cg     = (const float*)d_in[13];
    const float* cbe    = (const float*)d_in[14];
    const float* cm     = (const float*)d_in[15];
    const float* cv     = (const float*)d_in[16];
    const float* cW2    = (const float*)d_in[17];
    const float* cb2    = (const float*)d_in[18];
    const float* lin1_W = (const float*)d_in[19];
    const float* lin1_b = (const float*)d_in[20];
    const float* lin2_W = (const float*)d_in[21];
    const float* lin2_b = (const float*)d_in[22];

    const int* esrc = ei;
    const int* edst = ei + N_EDGES;

    // workspace carve (~77.7 MB)
    float* u0      = (float*)d_ws;                       // N*32
    float* hcat    = u0 + (size_t)N_NODES * HL;          // N*128
    float* Wc      = hcat + (size_t)N_NODES * DIM_IN;    // 128*32
    int*   row_ptr = (int*)(Wc + DIM_IN * HL);           // N+1
    int*   cursor  = row_ptr + (N_NODES + 1);            // N (also deg)
    int*   srcs    = cursor + N_NODES;                   // E
    int*   bsums   = srcs + N_EDGES;                     // 512
    int*   boffs   = bsums + 512;                        // 512

    const int NB_NODE = (N_NODES + 255) / 256;   // 391
    const int NB_EDGE = (N_EDGES + 255) / 256;
    const int NB_CONV = (N_NODES + 7) / 8;       // 12500
    const int NB_T64  = (N_NODES + 63) / 64;     // 1563

    hipMemsetAsync(cursor, 0, N_NODES * sizeof(int), stream);
    k_wc<<<16, 256, 0, stream>>>(W, c1_W1, Wc);
    k_xproj<<<NB_T64, 256, 0, stream>>>(x, Wc, u0);

    // CSR build (reused by all 4 convs)
    k_count<<<NB_EDGE, 256, 0, stream>>>(edst, cursor);
    k_scan1<<<NB_NODE, 256, 0, stream>>>(cursor, row_ptr, bsums);
    k_scan2<<<1, 512, 0, stream>>>(bsums, boffs, NB_NODE);
    k_scan3<<<NB_NODE, 256, 0, stream>>>(row_ptr, boffs, cursor);
    k_scatter<<<NB_EDGE, 256, 0, stream>>>(esrc, edst, cursor, srcs);

    // conv1: gather in projected u-space (W1 pre-folded)
    k_conv<<<NB_CONV, 256, 0, stream>>>(u0, HL, row_ptr, srcs, nullptr,
                                        c1_b1, c1_g, c1_be, c1_m, c1_v,
                                        c1_W2, c1_b2, hcat);
    // conv2..4: gather previous h slice directly from hcat (W1 applied post-agg)
    for (int i = 0; i < 3; ++i) {
        k_conv<<<NB_CONV, 256, 0, stream>>>(hcat + i * HL, DIM_IN, row_ptr, srcs,
                                            cW1 + i * HL * HL,
                                            cb1 + i * HL, cg + i * HL, cbe + i * HL,
                                            cm + i * HL, cv + i * HL,
                                            cW2 + i * HL * HL, cb2 + i * HL,
                                            hcat + (i + 1) * HL);
    }

    k_final<<<NB_T64, 256, 0, stream>>>(hcat, lin1_W, lin1_b, lin2_W, lin2_b,
                                        (float*)d_out);
}

// Round 3
// 950.470 us; speedup vs baseline: 1.4280x; 1.4280x over previous
//
#include <hip/hip_runtime.h>
#include <math.h>

#define N_NODES 100000
#define N_EDGES 3200000
#define DIM_IN 128
#define HL 32
#define DIM_OUT 40
#define BN_EPS 1e-5f

// ---------------- Wc = W @ c1_W1  (128x128 @ 128x32) ----------------
__global__ __launch_bounds__(256) void k_wc(const float* __restrict__ W,
                                            const float* __restrict__ W1,
                                            float* __restrict__ Wc) {
    int idx = blockIdx.x * 256 + threadIdx.x;   // 0..4095
    int i = idx >> 5;   // 0..127
    int j = idx & 31;   // 0..31
    float acc = 0.f;
    for (int k = 0; k < DIM_IN; ++k) acc += W[i * DIM_IN + k] * W1[k * HL + j];
    Wc[i * HL + j] = acc;
}

// ---------------- u = x @ Wc  ([N,128] @ [128,32]), 64 nodes/block ----------------
__global__ __launch_bounds__(256) void k_xproj(const float* __restrict__ x,
                                               const float* __restrict__ Wc,
                                               float* __restrict__ u) {
    __shared__ float xs[64][132];     // padded: row stride 132 -> bank shift 4
    __shared__ float Ws[DIM_IN * HL]; // 16 KB
    int t = threadIdx.x;
    int base = blockIdx.x * 64;
    for (int i = t; i < DIM_IN * HL / 4; i += 256)
        ((float4*)Ws)[i] = ((const float4*)Wc)[i];
    for (int i = t; i < 64 * 32; i += 256) {     // 2048 float4s
        int r = i >> 5, c4 = i & 31;
        float4 val;
        if (base + r < N_NODES) val = ((const float4*)x)[(size_t)(base + r) * 32 + c4];
        else val = make_float4(0.f, 0.f, 0.f, 0.f);
        *(float4*)&xs[r][c4 * 4] = val;
    }
    __syncthreads();
    int mg = t >> 3;      // 0..31 -> nodes 2mg, 2mg+1
    int cg = t & 7;       // cols cg*4..+3
    int n0 = mg * 2;
    float4 a0 = make_float4(0.f, 0.f, 0.f, 0.f);
    float4 a1 = make_float4(0.f, 0.f, 0.f, 0.f);
    for (int k = 0; k < DIM_IN; ++k) {
        float x0 = xs[n0][k], x1 = xs[n0 + 1][k];
        float4 b = ((float4*)Ws)[k * 8 + cg];
        a0.x += x0 * b.x; a0.y += x0 * b.y; a0.z += x0 * b.z; a0.w += x0 * b.w;
        a1.x += x1 * b.x; a1.y += x1 * b.y; a1.z += x1 * b.z; a1.w += x1 * b.w;
    }
    int node = base + n0;
    if (node < N_NODES)     ((float4*)u)[(size_t)node * 8 + cg] = a0;
    if (node + 1 < N_NODES) ((float4*)u)[(size_t)(node + 1) * 8 + cg] = a1;
}

// ---------------- CSR build ----------------
__global__ void k_count(const int* __restrict__ dst, int* __restrict__ deg) {
    int e = blockIdx.x * 256 + threadIdx.x;
    if (e < N_EDGES) atomicAdd(&deg[dst[e]], 1);
}

__global__ __launch_bounds__(256) void k_scan1(const int* __restrict__ deg,
                                               int* __restrict__ row_ptr,
                                               int* __restrict__ bsums) {
    __shared__ int s[256];
    int t = threadIdx.x;
    int i = blockIdx.x * 256 + t;
    int val = (i < N_NODES) ? deg[i] : 0;
    s[t] = val;
    __syncthreads();
    for (int off = 1; off < 256; off <<= 1) {
        int a = 0;
        if (t >= off) a = s[t - off];
        __syncthreads();
        s[t] += a;
        __syncthreads();
    }
    if (i < N_NODES) row_ptr[i] = s[t] - val;
    if (t == 255) bsums[blockIdx.x] = s[255];
}

__global__ __launch_bounds__(512) void k_scan2(const int* __restrict__ bsums,
                                               int* __restrict__ boffs, int nb) {
    __shared__ int s[512];
    int t = threadIdx.x;
    int val = (t < nb) ? bsums[t] : 0;
    s[t] = val;
    __syncthreads();
    for (int off = 1; off < 512; off <<= 1) {
        int a = 0;
        if (t >= off) a = s[t - off];
        __syncthreads();
        s[t] += a;
        __syncthreads();
    }
    if (t < nb) boffs[t] = s[t] - val;
}

__global__ void k_scan3(int* __restrict__ row_ptr, const int* __restrict__ boffs,
                        int* __restrict__ cursor) {
    int i = blockIdx.x * 256 + threadIdx.x;
    if (i < N_NODES) {
        int v = row_ptr[i] + boffs[i >> 8];
        row_ptr[i] = v;
        cursor[i] = v;
    }
    if (i == 0) row_ptr[N_NODES] = N_EDGES;
}

__global__ void k_scatter(const int* __restrict__ src, const int* __restrict__ dst,
                          int* __restrict__ cursor, int* __restrict__ srcs) {
    int e = blockIdx.x * 256 + threadIdx.x;
    if (e < N_EDGES) {
        int p = atomicAdd(&cursor[dst[e]], 1);
        srcs[p] = src[e];
    }
}

// ---- fused conv: gather-agg (+W1) + BN + ReLU + @W2 + b2 + ReLU -> hcat slice ----
// W1 == nullptr for conv1 (input already projected into u-space).
__global__ __launch_bounds__(256) void k_conv(const float* __restrict__ hsrc, int sstride,
                                              const int* __restrict__ row_ptr,
                                              const int* __restrict__ srcs,
                                              const float* __restrict__ W1,
                                              const float* __restrict__ b1,
                                              const float* __restrict__ g,
                                              const float* __restrict__ be,
                                              const float* __restrict__ m,
                                              const float* __restrict__ v,
                                              const float* __restrict__ W2,
                                              const float* __restrict__ b2,
                                              float* __restrict__ hout) {
    __shared__ float W1s[HL * HL];
    __shared__ float W2s[HL * HL];
    __shared__ float as_[8][HL + 1];
    __shared__ float ts[8][HL + 1];
    int t = threadIdx.x;
    bool hasW1 = (W1 != nullptr);
    for (int i = t; i < HL * HL; i += 256) {
        W2s[i] = W2[i];
        if (hasW1) W1s[i] = W1[i];
    }
    int slot = t >> 5, d = t & 31;
    int node = blockIdx.x * 8 + slot;
    float A = 0.f;
    int e0 = 0, e1 = 0;
    if (node < N_NODES) {
        A = hsrc[(size_t)node * sstride + d];
        e0 = row_ptr[node];
        e1 = row_ptr[node + 1];
    }
    for (int base = e0; base < e1; base += 32) {
        int p = base + d;
        int idx = srcs[p < e1 ? p : e1 - 1];
        int cnt = e1 - base; if (cnt > 32) cnt = 32;
        float a0 = 0.f, a1 = 0.f, a2 = 0.f, a3 = 0.f;
        int j = 0;
        for (; j + 4 <= cnt; j += 4) {
            int s0 = __shfl(idx, j + 0, 32);
            int s1 = __shfl(idx, j + 1, 32);
            int s2 = __shfl(idx, j + 2, 32);
            int s3 = __shfl(idx, j + 3, 32);
            a0 += hsrc[(size_t)s0 * sstride + d];
            a1 += hsrc[(size_t)s1 * sstride + d];
            a2 += hsrc[(size_t)s2 * sstride + d];
            a3 += hsrc[(size_t)s3 * sstride + d];
        }
        for (; j < cnt; ++j) a0 += hsrc[(size_t)__shfl(idx, j, 32) * sstride + d];
        A += (a0 + a1) + (a2 + a3);
    }
    // folded BN affine: t = (A@W1)*s + beta
    float s = g[d] * rsqrtf(v[d] + BN_EPS);
    float beta = (b1[d] - m[d]) * s + be[d];
    float tval;
    if (hasW1) {
        as_[slot][d] = A;
        __syncthreads();
        float acc = 0.f;
        #pragma unroll
        for (int k = 0; k < HL; ++k) acc += as_[slot][k] * W1s[k * HL + d];
        tval = fmaxf(acc * s + beta, 0.f);
    } else {
        tval = fmaxf(A * s + beta, 0.f);
        __syncthreads();   // match barrier count (hasW1 is block-uniform anyway)
    }
    ts[slot][d] = tval;
    __syncthreads();
    float h = b2[d];
    #pragma unroll
    for (int k = 0; k < HL; ++k) h += ts[slot][k] * W2s[k * HL + d];
    if (node < N_NODES) hout[(size_t)node * DIM_IN + d] = fmaxf(h, 0.f);
}

// ------- final: lin1 + ReLU + lin2 + log_softmax, 32 nodes/block, 4x4 acc -------
// 256 threads. LDS: sh_h 32x132 (16.9 KB) + shW 5120 floats (20 KB) = 37.4 KB.
// __launch_bounds__(256,4): cap VGPR at 128 (round-2 version spilled at 256).
__global__ __launch_bounds__(256, 4) void k_final(const float* __restrict__ hcat,
                                                  const float* __restrict__ W1,
                                                  const float* __restrict__ b1,
                                                  const float* __restrict__ W2,
                                                  const float* __restrict__ b2,
                                                  float* __restrict__ out) {
    __shared__ float sh_h[32][132];   // row stride 132 -> bank shift 4
    __shared__ float shW[5120];       // W1 32-row chunk (4096 floats) / W2 full (5120)
    int t = threadIdx.x;
    int base = blockIdx.x * 32;       // 3125 * 32 == 100000 exactly (no tail)
    // stage 32x128 hcat tile (1024 float4, 4 per thread)
    for (int i = t; i < 1024; i += 256) {
        int r = i >> 5, c4 = i & 31;
        *(float4*)&sh_h[r][c4 * 4] =
            ((const float4*)hcat)[(size_t)(base + r) * 32 + c4];
    }
    int cg = t & 31;          // col group: cols c0..c0+3
    int ng = t >> 5;          // node group: nodes n0..n0+3
    int c0 = cg * 4, n0 = ng * 4;
    float acc[4][4];
    float4 bias = ((const float4*)b1)[cg];
    #pragma unroll
    for (int i = 0; i < 4; ++i) {
        acc[i][0] = bias.x; acc[i][1] = bias.y; acc[i][2] = bias.z; acc[i][3] = bias.w;
    }
    // lin1: K chunked by 32 rows of W1 staged in shW
    for (int kk = 0; kk < DIM_IN; kk += 32) {
        __syncthreads();
        for (int i = t; i < 1024; i += 256)
            ((float4*)shW)[i] = ((const float4*)W1)[(size_t)(kk + (i >> 5)) * 32 + (i & 31)];
        __syncthreads();
        #pragma unroll 4
        for (int k = 0; k < 32; ++k) {
            float4 b = ((float4*)shW)[k * 32 + cg];
            #pragma unroll
            for (int i = 0; i < 4; ++i) {
                float a = sh_h[n0 + i][kk + k];
                acc[i][0] += a * b.x; acc[i][1] += a * b.y;
                acc[i][2] += a * b.z; acc[i][3] += a * b.w;
            }
        }
    }
    __syncthreads();
    // relu(t) back into sh_h; stage full W2 (5120 floats = 1280 float4, 5/thread)
    #pragma unroll
    for (int i = 0; i < 4; ++i) {
        float4 vv = make_float4(fmaxf(acc[i][0], 0.f), fmaxf(acc[i][1], 0.f),
                                fmaxf(acc[i][2], 0.f), fmaxf(acc[i][3], 0.f));
        *(float4*)&sh_h[n0 + i][c0] = vv;
    }
    for (int i = t; i < 1280; i += 256) ((float4*)shW)[i] = ((const float4*)W2)[i];
    __syncthreads();
    // lin2: thread -> node (t>>3), cols (t&7)*5 .. +4
    int nn = t >> 3;
    int c2 = (t & 7) * 5;
    float acc2[5];
    #pragma unroll
    for (int j = 0; j < 5; ++j) acc2[j] = b2[c2 + j];
    #pragma unroll 4
    for (int k = 0; k < DIM_IN; ++k) {
        float a = sh_h[nn][k];
        #pragma unroll
        for (int j = 0; j < 5; ++j) acc2[j] += a * shW[k * 40 + c2 + j];
    }
    // log_softmax across the 8 lanes owning this node
    float mx = acc2[0];
    #pragma unroll
    for (int j = 1; j < 5; ++j) mx = fmaxf(mx, acc2[j]);
    for (int off = 1; off < 8; off <<= 1) mx = fmaxf(mx, __shfl_xor(mx, off, 8));
    float sm = 0.f;
    #pragma unroll
    for (int j = 0; j < 5; ++j) sm += expf(acc2[j] - mx);
    for (int off = 1; off < 8; off <<= 1) sm += __shfl_xor(sm, off, 8);
    float lz = mx + logf(sm);
    int node = base + nn;
    #pragma unroll
    for (int j = 0; j < 5; ++j) {
        float o = acc2[j];
        out[(size_t)node * DIM_OUT + c2 + j] = o;
        out[(size_t)N_NODES * DIM_OUT + (size_t)node * DIM_OUT + c2 + j] = o - lz;
    }
}

extern "C" void kernel_launch(void* const* d_in, const int* in_sizes, int n_in,
                              void* d_out, int out_size, void* d_ws, size_t ws_size,
                              hipStream_t stream) {
    const float* x      = (const float*)d_in[0];
    const int*   ei     = (const int*)d_in[1];
    const float* W      = (const float*)d_in[2];
    const float* c1_W1  = (const float*)d_in[3];
    const float* c1_b1  = (const float*)d_in[4];
    const float* c1_g   = (const float*)d_in[5];
    const float* c1_be  = (const float*)d_in[6];
    const float* c1_m   = (const float*)d_in[7];
    const float* c1_v   = (const float*)d_in[8];
    const float* c1_W2  = (const float*)d_in[9];
    const float* c1_b2  = (const float*)d_in[10];
    const float* cW1    = (const float*)d_in[11];
    const float* cb1    = (const float*)d_in[12];
    const float* cg     = (const float*)d_in[13];
    const float* cbe    = (const float*)d_in[14];
    const float* cm     = (const float*)d_in[15];
    const float* cv     = (const float*)d_in[16];
    const float* cW2    = (const float*)d_in[17];
    const float* cb2    = (const float*)d_in[18];
    const float* lin1_W = (const float*)d_in[19];
    const float* lin1_b = (const float*)d_in[20];
    const float* lin2_W = (const float*)d_in[21];
    const float* lin2_b = (const float*)d_in[22];

    const int* esrc = ei;
    const int* edst = ei + N_EDGES;

    // workspace carve (~77.7 MB)
    float* u0      = (float*)d_ws;                       // N*32
    float* hcat    = u0 + (size_t)N_NODES * HL;          // N*128
    float* Wc      = hcat + (size_t)N_NODES * DIM_IN;    // 128*32
    int*   row_ptr = (int*)(Wc + DIM_IN * HL);           // N+1
    int*   cursor  = row_ptr + (N_NODES + 1);            // N (also deg)
    int*   srcs    = cursor + N_NODES;                   // E
    int*   bsums   = srcs + N_EDGES;                     // 512
    int*   boffs   = bsums + 512;                        // 512

    const int NB_NODE = (N_NODES + 255) / 256;   // 391
    const int NB_EDGE = (N_EDGES + 255) / 256;
    const int NB_CONV = (N_NODES + 7) / 8;       // 12500
    const int NB_T64  = (N_NODES + 63) / 64;     // 1563

    hipMemsetAsync(cursor, 0, N_NODES * sizeof(int), stream);
    k_wc<<<16, 256, 0, stream>>>(W, c1_W1, Wc);
    k_xproj<<<NB_T64, 256, 0, stream>>>(x, Wc, u0);

    // CSR build (reused by all 4 convs)
    k_count<<<NB_EDGE, 256, 0, stream>>>(edst, cursor);
    k_scan1<<<NB_NODE, 256, 0, stream>>>(cursor, row_ptr, bsums);
    k_scan2<<<1, 512, 0, stream>>>(bsums, boffs, NB_NODE);
    k_scan3<<<NB_NODE, 256, 0, stream>>>(row_ptr, boffs, cursor);
    k_scatter<<<NB_EDGE, 256, 0, stream>>>(esrc, edst, cursor, srcs);

    // conv1: gather in projected u-space (W1 pre-folded)
    k_conv<<<NB_CONV, 256, 0, stream>>>(u0, HL, row_ptr, srcs, nullptr,
                                        c1_b1, c1_g, c1_be, c1_m, c1_v,
                                        c1_W2, c1_b2, hcat);
    // conv2..4: gather previous h slice directly from hcat (W1 applied post-agg)
    for (int i = 0; i < 3; ++i) {
        k_conv<<<NB_CONV, 256, 0, stream>>>(hcat + i * HL, DIM_IN, row_ptr, srcs,
                                            cW1 + i * HL * HL,
                                            cb1 + i * HL, cg + i * HL, cbe + i * HL,
                                            cm + i * HL, cv + i * HL,
                                            cW2 + i * HL * HL, cb2 + i * HL,
                                            hcat + (i + 1) * HL);
    }

    k_final<<<N_NODES / 32, 256, 0, stream>>>(hcat, lin1_W, lin1_b, lin2_W, lin2_b,
                                              (float*)d_out);
}

// Round 5
// 897.975 us; speedup vs baseline: 1.5115x; 1.0585x over previous
//
#include <hip/hip_runtime.h>
#include <math.h>

#define N_NODES 100000
#define N_EDGES 3200000
#define DIM_IN 128
#define HL 32
#define DIM_OUT 40
#define BN_EPS 1e-5f

// bucket sort params: bucket = dst>>6 (64 nodes/bucket)
#define NBUCKET 1563            // ceil(100000/64)
#define NBLK 78                 // pass-1 blocks
#define TILE 41472              // 162*256 edges per pass-1 block (78*41472 >= 3.2M)
#define M_CNT (NBUCKET * NBLK)  // 121914 count-matrix entries

// ---------------- Wc = W @ c1_W1  (128x128 @ 128x32) ----------------
__global__ __launch_bounds__(256) void k_wc(const float* __restrict__ W,
                                            const float* __restrict__ W1,
                                            float* __restrict__ Wc) {
    int idx = blockIdx.x * 256 + threadIdx.x;   // 0..4095
    int i = idx >> 5;   // 0..127
    int j = idx & 31;   // 0..31
    float acc = 0.f;
    for (int k = 0; k < DIM_IN; ++k) acc += W[i * DIM_IN + k] * W1[k * HL + j];
    Wc[i * HL + j] = acc;
}

// ---------------- u = x @ Wc  ([N,128] @ [128,32]), 64 nodes/block ----------------
__global__ __launch_bounds__(256) void k_xproj(const float* __restrict__ x,
                                               const float* __restrict__ Wc,
                                               float* __restrict__ u) {
    __shared__ float xs[64][132];     // padded: row stride 132 -> bank shift 4
    __shared__ float Ws[DIM_IN * HL]; // 16 KB
    int t = threadIdx.x;
    int base = blockIdx.x * 64;
    for (int i = t; i < DIM_IN * HL / 4; i += 256)
        ((float4*)Ws)[i] = ((const float4*)Wc)[i];
    for (int i = t; i < 64 * 32; i += 256) {     // 2048 float4s
        int r = i >> 5, c4 = i & 31;
        float4 val;
        if (base + r < N_NODES) val = ((const float4*)x)[(size_t)(base + r) * 32 + c4];
        else val = make_float4(0.f, 0.f, 0.f, 0.f);
        *(float4*)&xs[r][c4 * 4] = val;
    }
    __syncthreads();
    int mg = t >> 3;      // 0..31 -> nodes 2mg, 2mg+1
    int cg = t & 7;       // cols cg*4..+3
    int n0 = mg * 2;
    float4 a0 = make_float4(0.f, 0.f, 0.f, 0.f);
    float4 a1 = make_float4(0.f, 0.f, 0.f, 0.f);
    for (int k = 0; k < DIM_IN; ++k) {
        float x0 = xs[n0][k], x1 = xs[n0 + 1][k];
        float4 b = ((float4*)Ws)[k * 8 + cg];
        a0.x += x0 * b.x; a0.y += x0 * b.y; a0.z += x0 * b.z; a0.w += x0 * b.w;
        a1.x += x1 * b.x; a1.y += x1 * b.y; a1.z += x1 * b.z; a1.w += x1 * b.w;
    }
    int node = base + n0;
    if (node < N_NODES)     ((float4*)u)[(size_t)node * 8 + cg] = a0;
    if (node + 1 < N_NODES) ((float4*)u)[(size_t)(node + 1) * 8 + cg] = a1;
}

// ---------------- node-degree histogram ----------------
__global__ void k_count(const int* __restrict__ dst, int* __restrict__ deg) {
    int e = blockIdx.x * 256 + threadIdx.x;
    if (e < N_EDGES) atomicAdd(&deg[dst[e]], 1);
}

// ---------------- generic 3-level exclusive scan ----------------
__global__ __launch_bounds__(256) void k_scan1(const int* __restrict__ in,
                                               int* __restrict__ outp,
                                               int* __restrict__ bsums, int n) {
    __shared__ int s[256];
    int t = threadIdx.x;
    int i = blockIdx.x * 256 + t;
    int val = (i < n) ? in[i] : 0;
    s[t] = val;
    __syncthreads();
    for (int off = 1; off < 256; off <<= 1) {
        int a = 0;
        if (t >= off) a = s[t - off];
        __syncthreads();
        s[t] += a;
        __syncthreads();
    }
    if (i < n) outp[i] = s[t] - val;   // exclusive within block
    if (t == 255) bsums[blockIdx.x] = s[255];
}

__global__ __launch_bounds__(512) void k_scan2(const int* __restrict__ bsums,
                                               int* __restrict__ boffs, int nb) {
    __shared__ int s[512];
    int t = threadIdx.x;
    int val = (t < nb) ? bsums[t] : 0;
    s[t] = val;
    __syncthreads();
    for (int off = 1; off < 512; off <<= 1) {
        int a = 0;
        if (t >= off) a = s[t - off];
        __syncthreads();
        s[t] += a;
        __syncthreads();
    }
    if (t < nb) boffs[t] = s[t] - val;
}

__global__ void k_scan3(int* __restrict__ arr, const int* __restrict__ boffs,
                        int n, int total, int write_total) {
    int i = blockIdx.x * 256 + threadIdx.x;
    if (i < n) arr[i] += boffs[i >> 8];
    if (write_total && i == 0) arr[n] = total;
}

// ---------------- pass 1a: per-block bucket histogram ----------------
__global__ __launch_bounds__(256) void k_hist(const int* __restrict__ dst,
                                              int* __restrict__ cnt) {
    __shared__ int bins[NBUCKET];
    int t = threadIdx.x, blk = blockIdx.x;
    for (int i = t; i < NBUCKET; i += 256) bins[i] = 0;
    __syncthreads();
    int e0 = blk * TILE;
    int e1 = e0 + TILE; if (e1 > N_EDGES) e1 = N_EDGES;
    for (int e = e0 + t; e < e1; e += 256)
        atomicAdd(&bins[dst[e] >> 6], 1);
    __syncthreads();
    for (int i = t; i < NBUCKET; i += 256) cnt[i * NBLK + blk] = bins[i];
}

// ---- pass 1b: bucket-partition edges into pairs (deterministic, no global atomics) ----
__global__ __launch_bounds__(256) void k_scatA(const int* __restrict__ src,
                                               const int* __restrict__ dst,
                                               const int* __restrict__ cnt,
                                               unsigned int* __restrict__ pairs) {
    __shared__ int cur[NBUCKET];
    int t = threadIdx.x, blk = blockIdx.x;
    for (int i = t; i < NBUCKET; i += 256) cur[i] = cnt[i * NBLK + blk];
    __syncthreads();
    int e0 = blk * TILE;
    int e1 = e0 + TILE; if (e1 > N_EDGES) e1 = N_EDGES;
    for (int e = e0 + t; e < e1; e += 256) {
        int d = dst[e];
        int p = atomicAdd(&cur[d >> 6], 1);
        pairs[p] = ((unsigned int)src[e] << 6) | (unsigned int)(d & 63);
    }
}

// ---- pass 2: within-bucket scatter to node order (LDS cursors, 8 KB window) ----
__global__ __launch_bounds__(256) void k_scatB(const unsigned int* __restrict__ pairs,
                                               const int* __restrict__ row_ptr,
                                               int* __restrict__ srcs) {
    __shared__ int cur[64];
    int t = threadIdx.x, b = blockIdx.x;
    int node0 = b << 6;
    if (t < 64) {
        int n = node0 + t;
        cur[t] = (n <= N_NODES) ? row_ptr[n] : N_EDGES;
    }
    __syncthreads();
    int i0 = row_ptr[node0];
    int nend = node0 + 64; if (nend > N_NODES) nend = N_NODES;
    int i1 = row_ptr[nend];
    for (int i = i0 + t; i < i1; i += 256) {
        unsigned int v = pairs[i];
        int p = atomicAdd(&cur[v & 63u], 1);
        srcs[p] = (int)(v >> 6);
    }
}

// ---- fused conv: gather-agg (+W1) + BN + ReLU + @W2 + b2 + ReLU -> hcat slice ----
// W1 == nullptr for conv1 (input already projected into u-space).
__global__ __launch_bounds__(256) void k_conv(const float* __restrict__ hsrc, int sstride,
                                              const int* __restrict__ row_ptr,
                                              const int* __restrict__ srcs,
                                              const float* __restrict__ W1,
                                              const float* __restrict__ b1,
                                              const float* __restrict__ g,
                                              const float* __restrict__ be,
                                              const float* __restrict__ m,
                                              const float* __restrict__ v,
                                              const float* __restrict__ W2,
                                              const float* __restrict__ b2,
                                              float* __restrict__ hout) {
    __shared__ float W1s[HL * HL];
    __shared__ float W2s[HL * HL];
    __shared__ float as_[8][HL + 1];
    __shared__ float ts[8][HL + 1];
    int t = threadIdx.x;
    bool hasW1 = (W1 != nullptr);
    for (int i = t; i < HL * HL; i += 256) {
        W2s[i] = W2[i];
        if (hasW1) W1s[i] = W1[i];
    }
    int slot = t >> 5, d = t & 31;
    int node = blockIdx.x * 8 + slot;
    float A = 0.f;
    int e0 = 0, e1 = 0;
    if (node < N_NODES) {
        A = hsrc[(size_t)node * sstride + d];
        e0 = row_ptr[node];
        e1 = row_ptr[node + 1];
    }
    for (int base = e0; base < e1; base += 32) {
        int p = base + d;
        int idx = srcs[p < e1 ? p : e1 - 1];
        int cnt = e1 - base; if (cnt > 32) cnt = 32;
        float a0 = 0.f, a1 = 0.f, a2 = 0.f, a3 = 0.f;
        int j = 0;
        for (; j + 4 <= cnt; j += 4) {
            int s0 = __shfl(idx, j + 0, 32);
            int s1 = __shfl(idx, j + 1, 32);
            int s2 = __shfl(idx, j + 2, 32);
            int s3 = __shfl(idx, j + 3, 32);
            a0 += hsrc[(size_t)s0 * sstride + d];
            a1 += hsrc[(size_t)s1 * sstride + d];
            a2 += hsrc[(size_t)s2 * sstride + d];
            a3 += hsrc[(size_t)s3 * sstride + d];
        }
        for (; j < cnt; ++j) a0 += hsrc[(size_t)__shfl(idx, j, 32) * sstride + d];
        A += (a0 + a1) + (a2 + a3);
    }
    // folded BN affine: t = (A@W1)*s + beta
    float s = g[d] * rsqrtf(v[d] + BN_EPS);
    float beta = (b1[d] - m[d]) * s + be[d];
    float tval;
    if (hasW1) {
        as_[slot][d] = A;
        __syncthreads();
        float acc = 0.f;
        #pragma unroll
        for (int k = 0; k < HL; ++k) acc += as_[slot][k] * W1s[k * HL + d];
        tval = fmaxf(acc * s + beta, 0.f);
    } else {
        tval = fmaxf(A * s + beta, 0.f);
        __syncthreads();   // match barrier count (hasW1 is block-uniform anyway)
    }
    ts[slot][d] = tval;
    __syncthreads();
    float h = b2[d];
    #pragma unroll
    for (int k = 0; k < HL; ++k) h += ts[slot][k] * W2s[k * HL + d];
    if (node < N_NODES) hout[(size_t)node * DIM_IN + d] = fmaxf(h, 0.f);
}

// ------- final: lin1 + ReLU + lin2 + log_softmax, 32 nodes/block, 4x4 acc -------
__global__ __launch_bounds__(256, 4) void k_final(const float* __restrict__ hcat,
                                                  const float* __restrict__ W1,
                                                  const float* __restrict__ b1,
                                                  const float* __restrict__ W2,
                                                  const float* __restrict__ b2,
                                                  float* __restrict__ out) {
    __shared__ float sh_h[32][132];   // row stride 132 -> bank shift 4
    __shared__ float shW[5120];       // W1 32-row chunk (4096 floats) / W2 full (5120)
    int t = threadIdx.x;
    int base = blockIdx.x * 32;       // 3125 * 32 == 100000 exactly (no tail)
    for (int i = t; i < 1024; i += 256) {
        int r = i >> 5, c4 = i & 31;
        *(float4*)&sh_h[r][c4 * 4] =
            ((const float4*)hcat)[(size_t)(base + r) * 32 + c4];
    }
    int cg = t & 31;          // col group: cols c0..c0+3
    int ng = t >> 5;          // node group: nodes n0..n0+3
    int c0 = cg * 4, n0 = ng * 4;
    float acc[4][4];
    float4 bias = ((const float4*)b1)[cg];
    #pragma unroll
    for (int i = 0; i < 4; ++i) {
        acc[i][0] = bias.x; acc[i][1] = bias.y; acc[i][2] = bias.z; acc[i][3] = bias.w;
    }
    for (int kk = 0; kk < DIM_IN; kk += 32) {
        __syncthreads();
        for (int i = t; i < 1024; i += 256)
            ((float4*)shW)[i] = ((const float4*)W1)[(size_t)(kk + (i >> 5)) * 32 + (i & 31)];
        __syncthreads();
        #pragma unroll 4
        for (int k = 0; k < 32; ++k) {
            float4 b = ((float4*)shW)[k * 32 + cg];
            #pragma unroll
            for (int i = 0; i < 4; ++i) {
                float a = sh_h[n0 + i][kk + k];
                acc[i][0] += a * b.x; acc[i][1] += a * b.y;
                acc[i][2] += a * b.z; acc[i][3] += a * b.w;
            }
        }
    }
    __syncthreads();
    #pragma unroll
    for (int i = 0; i < 4; ++i) {
        float4 vv = make_float4(fmaxf(acc[i][0], 0.f), fmaxf(acc[i][1], 0.f),
                                fmaxf(acc[i][2], 0.f), fmaxf(acc[i][3], 0.f));
        *(float4*)&sh_h[n0 + i][c0] = vv;
    }
    for (int i = t; i < 1280; i += 256) ((float4*)shW)[i] = ((const float4*)W2)[i];
    __syncthreads();
    int nn = t >> 3;
    int c2 = (t & 7) * 5;
    float acc2[5];
    #pragma unroll
    for (int j = 0; j < 5; ++j) acc2[j] = b2[c2 + j];
    #pragma unroll 4
    for (int k = 0; k < DIM_IN; ++k) {
        float a = sh_h[nn][k];
        #pragma unroll
        for (int j = 0; j < 5; ++j) acc2[j] += a * shW[k * 40 + c2 + j];
    }
    float mx = acc2[0];
    #pragma unroll
    for (int j = 1; j < 5; ++j) mx = fmaxf(mx, acc2[j]);
    for (int off = 1; off < 8; off <<= 1) mx = fmaxf(mx, __shfl_xor(mx, off, 8));
    float sm = 0.f;
    #pragma unroll
    for (int j = 0; j < 5; ++j) sm += expf(acc2[j] - mx);
    for (int off = 1; off < 8; off <<= 1) sm += __shfl_xor(sm, off, 8);
    float lz = mx + logf(sm);
    int node = base + nn;
    #pragma unroll
    for (int j = 0; j < 5; ++j) {
        float o = acc2[j];
        out[(size_t)node * DIM_OUT + c2 + j] = o;
        out[(size_t)N_NODES * DIM_OUT + (size_t)node * DIM_OUT + c2 + j] = o - lz;
    }
}

extern "C" void kernel_launch(void* const* d_in, const int* in_sizes, int n_in,
                              void* d_out, int out_size, void* d_ws, size_t ws_size,
                              hipStream_t stream) {
    const float* x      = (const float*)d_in[0];
    const int*   ei     = (const int*)d_in[1];
    const float* W      = (const float*)d_in[2];
    const float* c1_W1  = (const float*)d_in[3];
    const float* c1_b1  = (const float*)d_in[4];
    const float* c1_g   = (const float*)d_in[5];
    const float* c1_be  = (const float*)d_in[6];
    const float* c1_m   = (const float*)d_in[7];
    const float* c1_v   = (const float*)d_in[8];
    const float* c1_W2  = (const float*)d_in[9];
    const float* c1_b2  = (const float*)d_in[10];
    const float* cW1    = (const float*)d_in[11];
    const float* cb1    = (const float*)d_in[12];
    const float* cg     = (const float*)d_in[13];
    const float* cbe    = (const float*)d_in[14];
    const float* cm     = (const float*)d_in[15];
    const float* cv     = (const float*)d_in[16];
    const float* cW2    = (const float*)d_in[17];
    const float* cb2    = (const float*)d_in[18];
    const float* lin1_W = (const float*)d_in[19];
    const float* lin1_b = (const float*)d_in[20];
    const float* lin2_W = (const float*)d_in[21];
    const float* lin2_b = (const float*)d_in[22];

    const int* esrc = ei;
    const int* edst = ei + N_EDGES;

    // workspace carve (~78.6 MB)
    float* u0      = (float*)d_ws;                       // N*32 floats
    float* hcat    = u0 + (size_t)N_NODES * HL;          // N*128 floats
    unsigned int* pairs = (unsigned int*)hcat;           // alias: used before hcat is written
    float* Wc      = hcat + (size_t)N_NODES * DIM_IN;    // 128*32
    int*   row_ptr = (int*)(Wc + DIM_IN * HL);           // N+1
    int*   deg     = row_ptr + (N_NODES + 1);            // N
    int*   srcs    = deg + N_NODES;                      // E
    int*   cnt     = srcs + N_EDGES;                     // M_CNT
    int*   bsums   = cnt + M_CNT;                        // 512
    int*   boffs   = bsums + 512;                        // 512

    const int NB_NODE = (N_NODES + 255) / 256;   // 391
    const int NB_EDGE = (N_EDGES + 255) / 256;   // 12500
    const int NB_CONV = (N_NODES + 7) / 8;       // 12500
    const int NB_T64  = (N_NODES + 63) / 64;     // 1563
    const int NB_CNT  = (M_CNT + 255) / 256;     // 477

    hipMemsetAsync(deg, 0, N_NODES * sizeof(int), stream);
    k_wc<<<16, 256, 0, stream>>>(W, c1_W1, Wc);
    k_xproj<<<NB_T64, 256, 0, stream>>>(x, Wc, u0);

    // node CSR offsets
    k_count<<<NB_EDGE, 256, 0, stream>>>(edst, deg);
    k_scan1<<<NB_NODE, 256, 0, stream>>>(deg, row_ptr, bsums, N_NODES);
    k_scan2<<<1, 512, 0, stream>>>(bsums, boffs, NB_NODE);
    k_scan3<<<NB_NODE, 256, 0, stream>>>(row_ptr, boffs, N_NODES, N_EDGES, 1);

    // deterministic bucket partition (bucket = dst>>6); bucket base == row_ptr[64b]
    k_hist<<<NBLK, 256, 0, stream>>>(edst, cnt);
    k_scan1<<<NB_CNT, 256, 0, stream>>>(cnt, cnt, bsums, M_CNT);
    k_scan2<<<1, 512, 0, stream>>>(bsums, boffs, NB_CNT);
    k_scan3<<<NB_CNT, 256, 0, stream>>>(cnt, boffs, M_CNT, 0, 0);
    k_scatA<<<NBLK, 256, 0, stream>>>(esrc, edst, cnt, pairs);
    k_scatB<<<NBUCKET, 256, 0, stream>>>(pairs, row_ptr, srcs);

    // conv1: gather in projected u-space (W1 pre-folded)
    k_conv<<<NB_CONV, 256, 0, stream>>>(u0, HL, row_ptr, srcs, nullptr,
                                        c1_b1, c1_g, c1_be, c1_m, c1_v,
                                        c1_W2, c1_b2, hcat);
    // conv2..4: gather previous h slice directly from hcat (W1 applied post-agg)
    for (int i = 0; i < 3; ++i) {
        k_conv<<<NB_CONV, 256, 0, stream>>>(hcat + i * HL, DIM_IN, row_ptr, srcs,
                                            cW1 + i * HL * HL,
                                            cb1 + i * HL, cg + i * HL, cbe + i * HL,
                                            cm + i * HL, cv + i * HL,
                                            cW2 + i * HL * HL, cb2 + i * HL,
                                            hcat + (i + 1) * HL);
    }

    k_final<<<N_NODES / 32, 256, 0, stream>>>(hcat, lin1_W, lin1_b, lin2_W, lin2_b,
                                              (float*)d_out);
}